// Round 14
// baseline (205.621 us; speedup 1.0000x reference)
//
#include <hip/hip_runtime.h>
#include <hip/hip_bf16.h>
#include <math.h>

typedef __bf16 bf16;
typedef bf16 bf16x8 __attribute__((ext_vector_type(8)));
typedef bf16 bf16x4 __attribute__((ext_vector_type(4)));
typedef float f32x4 __attribute__((ext_vector_type(4)));
typedef unsigned int u32;

#define EMB 1024
#define NH 16
#define DK 64
#define SEQ 2048
#define NB 2
#define NTOK (NB*SEQ)

// attention scale folded into Q at the QKV epilogue: 0.125 * log2(e)
#define QSCALE 0.18033688011112043f

#if defined(__has_builtin)
#if __has_builtin(__builtin_amdgcn_exp2f)
#define EXP2(x) __builtin_amdgcn_exp2f(x)
#else
#define EXP2(x) exp2f(x)
#endif
#else
#define EXP2(x) exp2f(x)
#endif

// async global->LDS, 16B per lane; lds dst = wave-uniform base + lane*16
__device__ __forceinline__ void gl_lds16(const void* g, void* l) {
    __builtin_amdgcn_global_load_lds(
        (const __attribute__((address_space(1))) u32*)g,
        (__attribute__((address_space(3))) u32*)l, 16, 0, 0);
}

// XOR-swizzled 64-wide LDS tile: elem(row,col) -> row*64 + ((col/8 ^ row%8)*8) + col%8
// Staging: lane (lrow=lane>>3, lc=lane&7) fetches global colblk (lc^lrow) so the
// wave-uniform-dst global_load_lds lands pre-swizzled. Rows must be 8-aligned.
#define SWZ(row, colblk) (((row)*64) + ((((colblk) ^ ((row)&7)))*8))

// P buffer: plain rows padded to 72 elems (144 B): affine addressing, b64 writes
// 8B-aligned (<=2-way bank alias = free), b128 reads 16B-aligned & bank-balanced.
#define PSTR 72

// T1: XCD-aware chunked remap (bijective; requires nwg % 8 == 0).
__device__ __forceinline__ void xcd_remap(int gx, int* bx, int* by) {
    int gy  = gridDim.y;
    int nwg = gx * gy;
    int wg  = *by * gx + *bx;
    int per = nwg >> 3;
    int s   = (wg & 7) * per + (wg >> 3);
    *bx = s % gx;
    *by = s / gx;
}

// fp32 -> bf16 conversion for x / w_qkv / w_comb in one launch (y = segment)
// 8 floats/thread, one packed 16B bf16x8 store (scalar bf16 stores don't vectorize)
__global__ __launch_bounds__(256) void convert3(
    const float* __restrict__ s0, const float* __restrict__ s1,
    const float* __restrict__ s2,
    bf16* __restrict__ d0, bf16* __restrict__ d1, bf16* __restrict__ d2)
{
    const float* src; bf16* dst; int n;
    switch (blockIdx.y) {
        case 0:  src = s0; dst = d0; n = NTOK*EMB;  break;
        case 1:  src = s1; dst = d1; n = 3*EMB*EMB; break;
        default: src = s2; dst = d2; n = EMB*EMB;   break;
    }
    int i = (blockIdx.x * 256 + threadIdx.x) * 8;
    if (i + 7 < n) {
        float4 a = *(const float4*)(src + i);
        float4 b = *(const float4*)(src + i + 4);
        bf16x8 o;
        o[0] = (bf16)a.x; o[1] = (bf16)a.y; o[2] = (bf16)a.z; o[3] = (bf16)a.w;
        o[4] = (bf16)b.x; o[5] = (bf16)b.y; o[6] = (bf16)b.z; o[7] = (bf16)b.w;
        *(bf16x8*)(dst + i) = o;
    }
}

// ---------------------------------------------------------------------------
// GEMM: D[m,n] = sum_k A[m,k] * B[n,k]   (row-major, K-contiguous, bf16)
// 2-PHASE PREFETCH: distinct static double buffers; stage K-step t+1 right
// after the barrier, drain rides the NEXT barrier; ONE barrier per K-step.
// 4 waves, wave = (BM/2) x (BN/2) quadrant. MODE 0: BM=128, BN=192 ->
// grid (16,32) = 512 blocks = EXACTLY one scheduling round at 2 blocks/CU
// (was 768 blocks = 1.5 rounds with a half-occupancy tail); reuse also
// improves: 20 b128 / 48 MFMA = 0.417 reads/MFMA (was 0.5).
// MODE 1: BM=64, BN=128 (unchanged). Requires Kdim % 128 == 0.
// ---------------------------------------------------------------------------
template<int MODE, int BM, int BN>
__global__ __launch_bounds__(256) void gemm_bt(
    const bf16* __restrict__ Aa, const bf16* __restrict__ Bb,
    bf16* __restrict__ qb, bf16* __restrict__ kb, bf16* __restrict__ vtb,
    float* __restrict__ outc, int Kdim)
{
    constexpr int MI = BM / 32;                     // A frags per wave
    constexpr int NJ = BN / 32;                     // B frags per wave
    __shared__ __align__(16) bf16 At0[BM*64];
    __shared__ __align__(16) bf16 At1[BM*64];
    __shared__ __align__(16) bf16 Bt0[BN*64];
    __shared__ __align__(16) bf16 Bt1[BN*64];
    const int tid  = threadIdx.x;
    const int w    = tid >> 6, lane = tid & 63;
    const int quad = lane >> 4, l15 = lane & 15;
    const int wr   = w >> 1,   wc  = w & 1;
    int bx = blockIdx.x, by = blockIdx.y;
    xcd_remap(gridDim.x, &bx, &by);
    const int m0 = by * BM, n0 = bx * BN;
    const int lrow = lane >> 3;
    const int lswz = ((lane & 7) ^ lrow) * 8;       // swizzled global col offset

    f32x4 acc[MI][NJ] = {};

    auto stageAB = [&](int k0, bf16* At, bf16* Bt) {
        #pragma unroll
        for (int i = 0; i < BM/32; ++i) {
            int r = w*(BM/4) + i*8 + lrow;
            gl_lds16(Aa + (size_t)(m0 + r)*Kdim + k0 + lswz, At + (w*(BM/4) + i*8)*64);
        }
        #pragma unroll
        for (int i = 0; i < BN/32; ++i) {
            int r = w*(BN/4) + i*8 + lrow;
            gl_lds16(Bb + (size_t)(n0 + r)*Kdim + k0 + lswz, Bt + (w*(BN/4) + i*8)*64);
        }
    };

    auto computeAB = [&](const bf16* At, const bf16* Bt) {
        #pragma unroll
        for (int kk = 0; kk < 2; ++kk) {
            bf16x8 a[MI], b[NJ];
            #pragma unroll
            for (int i = 0; i < MI; ++i)
                a[i] = *(const bf16x8*)(At + SWZ(wr*(BM/2) + i*16 + l15, 4*kk + quad));
            #pragma unroll
            for (int j = 0; j < NJ; ++j)
                b[j] = *(const bf16x8*)(Bt + SWZ(wc*(BN/2) + j*16 + l15, 4*kk + quad));
            __builtin_amdgcn_s_setprio(1);
            #pragma unroll
            for (int i = 0; i < MI; ++i)
                #pragma unroll
                for (int j = 0; j < NJ; ++j)
                    acc[i][j] = __builtin_amdgcn_mfma_f32_16x16x32_bf16(a[i], b[j], acc[i][j], 0, 0, 0);
            __builtin_amdgcn_s_setprio(0);
        }
    };

    const int NT2 = Kdim >> 7;                      // pairs of 64-K steps
    stageAB(0, At0, Bt0);
    for (int t2 = 0; t2 < NT2; ++t2) {
        __syncthreads();                            // drains stage -> buf0
        stageAB(t2*128 + 64, At1, Bt1);             // in flight across compute
        computeAB(At0, Bt0);
        __syncthreads();                            // drains stage -> buf1
        if (t2 + 1 < NT2)
            stageAB(t2*128 + 128, At0, Bt0);
        computeAB(At1, Bt1);
    }

    for (int i = 0; i < MI; ++i) for (int j = 0; j < NJ; ++j) {
        int rb  = m0 + wr*(BM/2) + i*16 + quad*4;
        int col = n0 + wc*(BN/2) + j*16 + l15;
        if (MODE == 0) {
            int c = col >> 10, h = (col >> 6) & 15, d = col & 63;
            int b_ = rb >> 11, s = rb & 2047;
            int bh = b_*NH + h;
            if (c == 2) {
                bf16 tmp[4] __attribute__((aligned(8)));
                for (int r = 0; r < 4; ++r) tmp[r] = (bf16)acc[i][j][r];
                *(ushort4*)(vtb + ((size_t)bh*DK + d)*SEQ + s) = *(ushort4*)tmp;
            } else if (c == 0) {
                for (int r = 0; r < 4; ++r)
                    qb[((size_t)bh*SEQ + s + r)*DK + d] = (bf16)(acc[i][j][r] * QSCALE);
            } else {
                for (int r = 0; r < 4; ++r)
                    kb[((size_t)bh*SEQ + s + r)*DK + d] = (bf16)acc[i][j][r];
            }
        } else {
            for (int r = 0; r < 4; ++r)
                outc[(size_t)(rb + r)*EMB + col] = acc[i][j][r];
        }
    }
}

// ---------------------------------------------------------------------------
// Flash attention (8-wave structure, 49.3-50.8 us across 7 runs — the measured
// structural floor for this decomposition): block = (b,h) x 128 Q rows,
// 8 waves x 16 Q rows. SWAPPED QK: sc[j] = mfma(K, Q) -> lane (quad,l15)
// holds S[k=j*16+quad*4+r][qrow=l15]: packed b64 P stores, per-lane k-partial
// psum. PV A-frag = P[qrow=l15][k] via b128. K/V double-buffered in distinct
// static LDS arrays; prefetch issued right after each barrier, drains at the
// next. setprio around MFMA. XCD-swizzled grid.
// Falsified alternatives (counters in journal): role-split (r3 +2us),
// in-reg P 16x16 (r5 +8us), 4-wave reuse (r8 +5us), 4-domain (r11 +11.5us),
// 32x32 MFMA + in-reg P (r13 +2us). DO NOT TOUCH.
// ---------------------------------------------------------------------------
__global__ __launch_bounds__(512) void attn_kernel(
    const bf16* __restrict__ q, const bf16* __restrict__ k,
    const bf16* __restrict__ vt, bf16* __restrict__ out)
{
    __shared__ __align__(16) bf16 QP[8*16*PSTR];   // 18 KB: Q tile (64-stride), then P (72-stride)
    __shared__ __align__(16) bf16 Kt0[64*64];      // 8 KB each
    __shared__ __align__(16) bf16 Kt1[64*64];
    __shared__ __align__(16) bf16 Vt0[64*64];
    __shared__ __align__(16) bf16 Vt1[64*64];

    const int tid  = threadIdx.x;
    const int w    = tid >> 6, lane = tid & 63;
    const int quad = lane >> 4, l15 = lane & 15;
    int qt = blockIdx.x, bh = blockIdx.y;
    xcd_remap(gridDim.x, &qt, &bh);
    const int lrow = lane >> 3;
    const int lswz = ((lane & 7) ^ lrow) * 8;

    // stage Q tile (each wave stages exactly its own 16 rows, swizzled, 64-stride)
    for (int i = 0; i < 2; ++i) {
        int r = w*16 + i*8 + lrow;
        gl_lds16(q + ((size_t)bh*SEQ + qt*128 + r)*DK + lswz, QP + (w*16 + i*8)*64);
    }
    asm volatile("s_waitcnt vmcnt(0)" ::: "memory");

    bf16x8 qf[2];
    for (int kk = 0; kk < 2; ++kk)
        qf[kk] = *(const bf16x8*)(QP + SWZ(w*16 + l15, 4*kk + quad));

    bf16* Pw = QP + w * 16 * PSTR;                 // per-wave P region (16 x 72)

    f32x4 O[4] = {};
    float psum = 0.f;                              // per-lane k-partial for qrow=l15

    auto stage_kv = [&](int kt, bf16* Kb, bf16* Vb) {
        int r = w*8 + lrow;
        gl_lds16(k  + ((size_t)bh*SEQ + kt*64 + r)*DK + lswz, Kb + (w*8)*64);
        gl_lds16(vt + ((size_t)bh*DK + r)*SEQ + kt*64 + lswz, Vb + (w*8)*64);
    };

    auto compute = [&](const bf16* Kb, const bf16* Vb) {
        f32x4 sc[4] = {};
        for (int kk = 0; kk < 2; ++kk) {
            bf16x8 kf[4];
            for (int j = 0; j < 4; ++j)
                kf[j] = *(const bf16x8*)(Kb + SWZ(j*16 + l15, 4*kk + quad));
            __builtin_amdgcn_s_setprio(1);
            for (int j = 0; j < 4; ++j)
                sc[j] = __builtin_amdgcn_mfma_f32_16x16x32_bf16(kf[j], qf[kk], sc[j], 0, 0, 0);
            __builtin_amdgcn_s_setprio(0);
        }
        // lane holds S[k=j*16+quad*4+r][qrow=l15]; p = 2^s (Q pre-scaled).
        // 4 consecutive k per j -> one packed 8B store per j.
        for (int j = 0; j < 4; ++j) {
            bf16x4 pk;
            for (int r = 0; r < 4; ++r) {
                float p = EXP2(sc[j][r]);
                psum += p;
                pk[r] = (bf16)p;
            }
            *(bf16x4*)(Pw + l15*PSTR + j*16 + quad*4) = pk;
        }
        asm volatile("s_waitcnt lgkmcnt(0)" ::: "memory");
        for (int kk = 0; kk < 2; ++kk) {
            bf16x8 vb[4];
            for (int j = 0; j < 4; ++j)
                vb[j] = *(const bf16x8*)(Vb + SWZ(j*16 + l15, 4*kk + quad));
            bf16x8 a = *(const bf16x8*)(Pw + l15*PSTR + kk*32 + quad*8);
            __builtin_amdgcn_s_setprio(1);
            for (int j = 0; j < 4; ++j)
                O[j] = __builtin_amdgcn_mfma_f32_16x16x32_bf16(a, vb[j], O[j], 0, 0, 0);
            __builtin_amdgcn_s_setprio(0);
        }
    };

    stage_kv(0, Kt0, Vt0);
    for (int kt2 = 0; kt2 < SEQ/128; ++kt2) {
        __syncthreads();                            // drains KV(2*kt2) -> buf0
        stage_kv(2*kt2 + 1, Kt1, Vt1);              // in flight across compute
        compute(Kt0, Vt0);
        __syncthreads();                            // drains KV(2*kt2+1) -> buf1
        if (kt2 + 1 < SEQ/128)
            stage_kv(2*kt2 + 2, Kt0, Vt0);
        compute(Kt1, Vt1);
    }

    // psum: reduce over quads (k-partials), then fetch per-output-row sums
    float s = psum;
    s += __shfl_xor(s, 16, 64);
    s += __shfl_xor(s, 32, 64);                    // all lanes: total for qrow=l15
    float inv[4];
    for (int r = 0; r < 4; ++r)
        inv[r] = 1.f / __shfl(s, quad*4 + r, 64);  // sum for qrow=quad*4+r

    const int b_ = bh >> 4, h = bh & 15;
    for (int j = 0; j < 4; ++j)
        for (int r = 0; r < 4; ++r) {
            int t   = b_*SEQ + qt*128 + w*16 + quad*4 + r;
            int col = h*DK + j*16 + l15;
            out[(size_t)t*EMB + col] = (bf16)(O[j][r] * inv[r]);
        }
}

// ---------------------------------------------------------------------------
// Per-token LN chain, ONE WAVE PER TOKEN (4 tokens / 256-block): no barriers,
// no LDS — all reductions via width-64 shuffles.
// ---------------------------------------------------------------------------
__global__ __launch_bounds__(256) void ln_kernel(
    const float* __restrict__ x, const float* __restrict__ comb,
    const float* __restrict__ bcomb,
    const float* __restrict__ g1, const float* __restrict__ be1,
    const float* __restrict__ g2, const float* __restrict__ be2,
    const float* __restrict__ theta, const float* __restrict__ w1v,
    const float* __restrict__ b1v, float* __restrict__ out)
{
    const int w    = threadIdx.x >> 6, lane = threadIdx.x & 63;
    const int t    = blockIdx.x * 4 + w;

    float r[4][4];
    float s = 0.f, ss = 0.f;
    #pragma unroll
    for (int c = 0; c < 4; ++c) {
        int e = c*256 + lane*4;
        float4 xv = *(const float4*)(x    + (size_t)t*EMB + e);
        float4 cv = *(const float4*)(comb + (size_t)t*EMB + e);
        float4 bv = *(const float4*)(bcomb + e);
        r[c][0] = xv.x + cv.x + bv.x; r[c][1] = xv.y + cv.y + bv.y;
        r[c][2] = xv.z + cv.z + bv.z; r[c][3] = xv.w + cv.w + bv.w;
        #pragma unroll
        for (int i = 0; i < 4; ++i) { s += r[c][i]; ss += r[c][i]*r[c][i]; }
    }
    #pragma unroll
    for (int m = 1; m < 64; m <<= 1) { s += __shfl_xor(s, m, 64); ss += __shfl_xor(ss, m, 64); }
    float mean = s * (1.f/1024.f);
    float var  = ss * (1.f/1024.f) - mean*mean;
    float inv  = rsqrtf(var + 1e-5f);

    float x1[4][4];
    #pragma unroll
    for (int c = 0; c < 4; ++c) {
        int e = c*256 + lane*4;
        #pragma unroll
        for (int i = 0; i < 4; ++i)
            x1[c][i] = (r[c][i] - mean)*inv*g1[e+i] + be1[e+i];
    }

    // quantum FFN: elems 0..7 live in lanes 0 (e=0..3) and 1 (e=4..7), chunk 0
    float pf = 0.f;
    if (lane < 2) {
        #pragma unroll
        for (int i = 0; i < 4; ++i) {
            int e = lane*4 + i;
            pf += cosf(x1[0][i]) * cosf(theta[e]) * w1v[e];
        }
    }
    pf += __shfl_xor(pf, 1, 64);
    float f = __shfl(pf, 0, 64) + b1v[0];

    float s2 = 0.f, ss2 = 0.f;
    #pragma unroll
    for (int c = 0; c < 4; ++c)
        #pragma unroll
        for (int i = 0; i < 4; ++i) {
            float v2 = x1[c][i] + f; s2 += v2; ss2 += v2*v2;
        }
    #pragma unroll
    for (int m = 1; m < 64; m <<= 1) { s2 += __shfl_xor(s2, m, 64); ss2 += __shfl_xor(ss2, m, 64); }
    float mean2 = s2 * (1.f/1024.f);
    float var2  = ss2 * (1.f/1024.f) - mean2*mean2;
    float inv2  = rsqrtf(var2 + 1e-5f);

    #pragma unroll
    for (int c = 0; c < 4; ++c) {
        int e = c*256 + lane*4;
        float4 ov;
        ov.x = ((x1[c][0] + f) - mean2)*inv2*g2[e+0] + be2[e+0];
        ov.y = ((x1[c][1] + f) - mean2)*inv2*g2[e+1] + be2[e+1];
        ov.z = ((x1[c][2] + f) - mean2)*inv2*g2[e+2] + be2[e+2];
        ov.w = ((x1[c][3] + f) - mean2)*inv2*g2[e+3] + be2[e+3];
        *(float4*)(out + (size_t)t*EMB + e) = ov;
    }
}

extern "C" void kernel_launch(void* const* d_in, const int* in_sizes, int n_in,
                              void* d_out, int out_size, void* d_ws, size_t ws_size,
                              hipStream_t stream)
{
    const float* x      = (const float*)d_in[0];
    const float* w_qkv  = (const float*)d_in[1];
    const float* w_comb = (const float*)d_in[2];
    const float* b_comb = (const float*)d_in[3];
    const float* g1     = (const float*)d_in[4];
    const float* be1    = (const float*)d_in[5];
    const float* g2     = (const float*)d_in[6];
    const float* be2    = (const float*)d_in[7];
    const float* theta  = (const float*)d_in[8];
    const float* w1v    = (const float*)d_in[9];
    const float* b1v    = (const float*)d_in[10];
    float* out = (float*)d_out;

    char* ws = (char*)d_ws;
    bf16*  xb     = (bf16*)(ws);                    // [ 0,  8) MB
    bf16*  wqkvb  = (bf16*)(ws + ( 8u<<20));        // [ 8, 14) MB
    bf16*  wcombb = (bf16*)(ws + (14u<<20));        // [14, 16) MB
    bf16*  qb     = (bf16*)(ws + (16u<<20));        // [16, 24) MB
    bf16*  kb     = (bf16*)(ws + (24u<<20));        // [24, 32) MB
    bf16*  vtb    = (bf16*)(ws + (32u<<20));        // [32, 40) MB
    bf16*  attn   = (bf16*)(ws + (40u<<20));        // [40, 48) MB
    float* comb   = (float*)(ws + (16u<<20));       // [16, 32) MB (aliases dead q,k)

    convert3<<<dim3(2048, 3), 256, 0, stream>>>(x, w_qkv, w_comb, xb, wqkvb, wcombb);

    gemm_bt<0,128,192><<<dim3(3*EMB/192, NTOK/128), 256, 0, stream>>>(
        xb, wqkvb, qb, kb, vtb, nullptr, EMB);
    attn_kernel<<<dim3(SEQ/128, NB*NH), 512, 0, stream>>>(qb, kb, vtb, attn);
    gemm_bt<1,64,128><<<dim3(EMB/128, NTOK/64), 256, 0, stream>>>(
        attn, wcombb, nullptr, nullptr, nullptr, comb, EMB);
    ln_kernel<<<NTOK/4, 256, 0, stream>>>(x, comb, b_comb, g1, be1, g2, be2,
                                          theta, w1v, b1v, out);
}

// Round 16
// 193.543 us; speedup vs baseline: 1.0624x; 1.0624x over previous
//
#include <hip/hip_runtime.h>
#include <hip/hip_bf16.h>
#include <math.h>

typedef __bf16 bf16;
typedef bf16 bf16x8 __attribute__((ext_vector_type(8)));
typedef bf16 bf16x4 __attribute__((ext_vector_type(4)));
typedef float f32x4 __attribute__((ext_vector_type(4)));
typedef unsigned int u32;

#define EMB 1024
#define NH 16
#define DK 64
#define SEQ 2048
#define NB 2
#define NTOK (NB*SEQ)

// attention scale folded into Q at the QKV epilogue: 0.125 * log2(e)
#define QSCALE 0.18033688011112043f

#if defined(__has_builtin)
#if __has_builtin(__builtin_amdgcn_exp2f)
#define EXP2(x) __builtin_amdgcn_exp2f(x)
#else
#define EXP2(x) exp2f(x)
#endif
#else
#define EXP2(x) exp2f(x)
#endif

// async global->LDS, 16B per lane; lds dst = wave-uniform base + lane*16
__device__ __forceinline__ void gl_lds16(const void* g, void* l) {
    __builtin_amdgcn_global_load_lds(
        (const __attribute__((address_space(1))) u32*)g,
        (__attribute__((address_space(3))) u32*)l, 16, 0, 0);
}

// XOR-swizzled 64-wide LDS tile: elem(row,col) -> row*64 + ((col/8 ^ row%8)*8) + col%8
// Staging: lane (lrow=lane>>3, lc=lane&7) fetches global colblk (lc^lrow) so the
// wave-uniform-dst global_load_lds lands pre-swizzled. Rows must be 8-aligned.
#define SWZ(row, colblk) (((row)*64) + ((((colblk) ^ ((row)&7)))*8))

// P buffer: plain rows padded to 72 elems (144 B): affine addressing, b64 writes
// 8B-aligned (<=2-way bank alias = free), b128 reads 16B-aligned & bank-balanced.
#define PSTR 72

// T1: XCD-aware chunked remap (bijective; requires nwg % 8 == 0).
__device__ __forceinline__ void xcd_remap(int gx, int* bx, int* by) {
    int gy  = gridDim.y;
    int nwg = gx * gy;
    int wg  = *by * gx + *bx;
    int per = nwg >> 3;
    int s   = (wg & 7) * per + (wg >> 3);
    *bx = s % gx;
    *by = s / gx;
}

// fp32 -> bf16 conversion for x / w_qkv / w_comb in one launch (y = segment)
// 8 floats/thread, one packed 16B bf16x8 store (scalar bf16 stores don't vectorize)
__global__ __launch_bounds__(256) void convert3(
    const float* __restrict__ s0, const float* __restrict__ s1,
    const float* __restrict__ s2,
    bf16* __restrict__ d0, bf16* __restrict__ d1, bf16* __restrict__ d2)
{
    const float* src; bf16* dst; int n;
    switch (blockIdx.y) {
        case 0:  src = s0; dst = d0; n = NTOK*EMB;  break;
        case 1:  src = s1; dst = d1; n = 3*EMB*EMB; break;
        default: src = s2; dst = d2; n = EMB*EMB;   break;
    }
    int i = (blockIdx.x * 256 + threadIdx.x) * 8;
    if (i + 7 < n) {
        float4 a = *(const float4*)(src + i);
        float4 b = *(const float4*)(src + i + 4);
        bf16x8 o;
        o[0] = (bf16)a.x; o[1] = (bf16)a.y; o[2] = (bf16)a.z; o[3] = (bf16)a.w;
        o[4] = (bf16)b.x; o[5] = (bf16)b.y; o[6] = (bf16)b.z; o[7] = (bf16)b.w;
        *(bf16x8*)(dst + i) = o;
    }
}

// ---------------------------------------------------------------------------
// GEMM: D[m,n] = sum_k A[m,k] * B[n,k]   (row-major, K-contiguous, bf16)
// 2-PHASE PREFETCH: distinct static double buffers; stage K-step t+1 right
// after the barrier, drain rides the NEXT barrier; ONE barrier per K-step.
// 4 waves, wave = (BM/2) x 64 quadrant (the reuse optimum; r9: 8-wave = net
// loss; r14: BN=192 tail-elimination = net loss, tail is cheaper than the
// wider tile's staging+register cost).
// MODE 0 (BM=128): scatter q*QSCALE, k + packed vT. MODE 1: fp32 row-major.
// ---------------------------------------------------------------------------
template<int MODE, int BM>
__global__ __launch_bounds__(256) void gemm_bt(
    const bf16* __restrict__ Aa, const bf16* __restrict__ Bb,
    bf16* __restrict__ qb, bf16* __restrict__ kb, bf16* __restrict__ vtb,
    float* __restrict__ outc, int Kdim)
{
    constexpr int MI = BM / 32;
    __shared__ __align__(16) bf16 At0[BM*64];
    __shared__ __align__(16) bf16 At1[BM*64];
    __shared__ __align__(16) bf16 Bt0[128*64];
    __shared__ __align__(16) bf16 Bt1[128*64];
    const int tid  = threadIdx.x;
    const int w    = tid >> 6, lane = tid & 63;
    const int quad = lane >> 4, l15 = lane & 15;
    const int wr   = w >> 1,   wc  = w & 1;
    int bx = blockIdx.x, by = blockIdx.y;
    xcd_remap(gridDim.x, &bx, &by);
    const int m0 = by * BM, n0 = bx * 128;
    const int lrow = lane >> 3;
    const int lswz = ((lane & 7) ^ lrow) * 8;       // swizzled global col offset

    f32x4 acc[MI][4] = {};

    auto stageAB = [&](int k0, bf16* At, bf16* Bt) {
        #pragma unroll
        for (int i = 0; i < MI; ++i) {
            int r = w*(BM/4) + i*8 + lrow;
            gl_lds16(Aa + (size_t)(m0 + r)*Kdim + k0 + lswz, At + (w*(BM/4) + i*8)*64);
        }
        #pragma unroll
        for (int i = 0; i < 4; ++i) {
            int r = w*32 + i*8 + lrow;
            gl_lds16(Bb + (size_t)(n0 + r)*Kdim + k0 + lswz, Bt + (w*32 + i*8)*64);
        }
    };

    auto computeAB = [&](const bf16* At, const bf16* Bt) {
        #pragma unroll
        for (int kk = 0; kk < 2; ++kk) {
            bf16x8 a[MI], b[4];
            #pragma unroll
            for (int i = 0; i < MI; ++i)
                a[i] = *(const bf16x8*)(At + SWZ(wr*(BM/2) + i*16 + l15, 4*kk + quad));
            #pragma unroll
            for (int j = 0; j < 4; ++j)
                b[j] = *(const bf16x8*)(Bt + SWZ(wc*64 + j*16 + l15, 4*kk + quad));
            __builtin_amdgcn_s_setprio(1);
            #pragma unroll
            for (int i = 0; i < MI; ++i)
                #pragma unroll
                for (int j = 0; j < 4; ++j)
                    acc[i][j] = __builtin_amdgcn_mfma_f32_16x16x32_bf16(a[i], b[j], acc[i][j], 0, 0, 0);
            __builtin_amdgcn_s_setprio(0);
        }
    };

    const int NT2 = Kdim >> 7;                      // pairs of 64-K steps
    stageAB(0, At0, Bt0);
    for (int t2 = 0; t2 < NT2; ++t2) {
        __syncthreads();                            // drains stage -> buf0
        stageAB(t2*128 + 64, At1, Bt1);             // in flight across compute
        computeAB(At0, Bt0);
        __syncthreads();                            // drains stage -> buf1
        if (t2 + 1 < NT2)
            stageAB(t2*128 + 128, At0, Bt0);
        computeAB(At1, Bt1);
    }

    for (int i = 0; i < MI; ++i) for (int j = 0; j < 4; ++j) {
        int rb  = m0 + wr*(BM/2) + i*16 + quad*4;
        int col = n0 + wc*64 + j*16 + l15;
        if (MODE == 0) {
            int c = col >> 10, h = (col >> 6) & 15, d = col & 63;
            int b_ = rb >> 11, s = rb & 2047;
            int bh = b_*NH + h;
            if (c == 2) {
                bf16 tmp[4] __attribute__((aligned(8)));
                for (int r = 0; r < 4; ++r) tmp[r] = (bf16)acc[i][j][r];
                *(ushort4*)(vtb + ((size_t)bh*DK + d)*SEQ + s) = *(ushort4*)tmp;
            } else if (c == 0) {
                for (int r = 0; r < 4; ++r)
                    qb[((size_t)bh*SEQ + s + r)*DK + d] = (bf16)(acc[i][j][r] * QSCALE);
            } else {
                for (int r = 0; r < 4; ++r)
                    kb[((size_t)bh*SEQ + s + r)*DK + d] = (bf16)acc[i][j][r];
            }
        } else {
            for (int r = 0; r < 4; ++r)
                outc[(size_t)(rb + r)*EMB + col] = acc[i][j][r];
        }
    }
}

// ---------------------------------------------------------------------------
// Flash attention (8-wave structure, 49.3-50.8 us across 8 runs — the measured
// structural floor for this decomposition): block = (b,h) x 128 Q rows,
// 8 waves x 16 Q rows. SWAPPED QK: sc[j] = mfma(K, Q) -> lane (quad,l15)
// holds S[k=j*16+quad*4+r][qrow=l15]: packed b64 P stores, per-lane k-partial
// psum. PV A-frag = P[qrow=l15][k] via b128. K/V double-buffered in distinct
// static LDS arrays; prefetch issued right after each barrier, drains at the
// next. setprio around MFMA. XCD-swizzled grid.
// Falsified alternatives (counters in journal): role-split (r3 +2us),
// in-reg P 16x16 (r5 +8us), 4-wave reuse (r8 +5us), 4-domain (r11 +11.5us),
// 32x32 MFMA + in-reg P (r13 +2us). DO NOT TOUCH.
// ---------------------------------------------------------------------------
__global__ __launch_bounds__(512) void attn_kernel(
    const bf16* __restrict__ q, const bf16* __restrict__ k,
    const bf16* __restrict__ vt, bf16* __restrict__ out)
{
    __shared__ __align__(16) bf16 QP[8*16*PSTR];   // 18 KB: Q tile (64-stride), then P (72-stride)
    __shared__ __align__(16) bf16 Kt0[64*64];      // 8 KB each
    __shared__ __align__(16) bf16 Kt1[64*64];
    __shared__ __align__(16) bf16 Vt0[64*64];
    __shared__ __align__(16) bf16 Vt1[64*64];

    const int tid  = threadIdx.x;
    const int w    = tid >> 6, lane = tid & 63;
    const int quad = lane >> 4, l15 = lane & 15;
    int qt = blockIdx.x, bh = blockIdx.y;
    xcd_remap(gridDim.x, &qt, &bh);
    const int lrow = lane >> 3;
    const int lswz = ((lane & 7) ^ lrow) * 8;

    // stage Q tile (each wave stages exactly its own 16 rows, swizzled, 64-stride)
    for (int i = 0; i < 2; ++i) {
        int r = w*16 + i*8 + lrow;
        gl_lds16(q + ((size_t)bh*SEQ + qt*128 + r)*DK + lswz, QP + (w*16 + i*8)*64);
    }
    asm volatile("s_waitcnt vmcnt(0)" ::: "memory");

    bf16x8 qf[2];
    for (int kk = 0; kk < 2; ++kk)
        qf[kk] = *(const bf16x8*)(QP + SWZ(w*16 + l15, 4*kk + quad));

    bf16* Pw = QP + w * 16 * PSTR;                 // per-wave P region (16 x 72)

    f32x4 O[4] = {};
    float psum = 0.f;                              // per-lane k-partial for qrow=l15

    auto stage_kv = [&](int kt, bf16* Kb, bf16* Vb) {
        int r = w*8 + lrow;
        gl_lds16(k  + ((size_t)bh*SEQ + kt*64 + r)*DK + lswz, Kb + (w*8)*64);
        gl_lds16(vt + ((size_t)bh*DK + r)*SEQ + kt*64 + lswz, Vb + (w*8)*64);
    };

    auto compute = [&](const bf16* Kb, const bf16* Vb) {
        f32x4 sc[4] = {};
        for (int kk = 0; kk < 2; ++kk) {
            bf16x8 kf[4];
            for (int j = 0; j < 4; ++j)
                kf[j] = *(const bf16x8*)(Kb + SWZ(j*16 + l15, 4*kk + quad));
            __builtin_amdgcn_s_setprio(1);
            for (int j = 0; j < 4; ++j)
                sc[j] = __builtin_amdgcn_mfma_f32_16x16x32_bf16(kf[j], qf[kk], sc[j], 0, 0, 0);
            __builtin_amdgcn_s_setprio(0);
        }
        // lane holds S[k=j*16+quad*4+r][qrow=l15]; p = 2^s (Q pre-scaled).
        // 4 consecutive k per j -> one packed 8B store per j.
        for (int j = 0; j < 4; ++j) {
            bf16x4 pk;
            for (int r = 0; r < 4; ++r) {
                float p = EXP2(sc[j][r]);
                psum += p;
                pk[r] = (bf16)p;
            }
            *(bf16x4*)(Pw + l15*PSTR + j*16 + quad*4) = pk;
        }
        asm volatile("s_waitcnt lgkmcnt(0)" ::: "memory");
        for (int kk = 0; kk < 2; ++kk) {
            bf16x8 vb[4];
            for (int j = 0; j < 4; ++j)
                vb[j] = *(const bf16x8*)(Vb + SWZ(j*16 + l15, 4*kk + quad));
            bf16x8 a = *(const bf16x8*)(Pw + l15*PSTR + kk*32 + quad*8);
            __builtin_amdgcn_s_setprio(1);
            for (int j = 0; j < 4; ++j)
                O[j] = __builtin_amdgcn_mfma_f32_16x16x32_bf16(a, vb[j], O[j], 0, 0, 0);
            __builtin_amdgcn_s_setprio(0);
        }
    };

    stage_kv(0, Kt0, Vt0);
    for (int kt2 = 0; kt2 < SEQ/128; ++kt2) {
        __syncthreads();                            // drains KV(2*kt2) -> buf0
        stage_kv(2*kt2 + 1, Kt1, Vt1);              // in flight across compute
        compute(Kt0, Vt0);
        __syncthreads();                            // drains KV(2*kt2+1) -> buf1
        if (kt2 + 1 < SEQ/128)
            stage_kv(2*kt2 + 2, Kt0, Vt0);
        compute(Kt1, Vt1);
    }

    // psum: reduce over quads (k-partials), then fetch per-output-row sums
    float s = psum;
    s += __shfl_xor(s, 16, 64);
    s += __shfl_xor(s, 32, 64);                    // all lanes: total for qrow=l15
    float inv[4];
    for (int r = 0; r < 4; ++r)
        inv[r] = 1.f / __shfl(s, quad*4 + r, 64);  // sum for qrow=quad*4+r

    const int b_ = bh >> 4, h = bh & 15;
    for (int j = 0; j < 4; ++j)
        for (int r = 0; r < 4; ++r) {
            int t   = b_*SEQ + qt*128 + w*16 + quad*4 + r;
            int col = h*DK + j*16 + l15;
            out[(size_t)t*EMB + col] = (bf16)(O[j][r] * inv[r]);
        }
}

// ---------------------------------------------------------------------------
// Per-token LN chain, ONE WAVE PER TOKEN (4 tokens / 256-block): no barriers,
// no LDS — all reductions via width-64 shuffles.
// ---------------------------------------------------------------------------
__global__ __launch_bounds__(256) void ln_kernel(
    const float* __restrict__ x, const float* __restrict__ comb,
    const float* __restrict__ bcomb,
    const float* __restrict__ g1, const float* __restrict__ be1,
    const float* __restrict__ g2, const float* __restrict__ be2,
    const float* __restrict__ theta, const float* __restrict__ w1v,
    const float* __restrict__ b1v, float* __restrict__ out)
{
    const int w    = threadIdx.x >> 6, lane = threadIdx.x & 63;
    const int t    = blockIdx.x * 4 + w;

    float r[4][4];
    float s = 0.f, ss = 0.f;
    #pragma unroll
    for (int c = 0; c < 4; ++c) {
        int e = c*256 + lane*4;
        float4 xv = *(const float4*)(x    + (size_t)t*EMB + e);
        float4 cv = *(const float4*)(comb + (size_t)t*EMB + e);
        float4 bv = *(const float4*)(bcomb + e);
        r[c][0] = xv.x + cv.x + bv.x; r[c][1] = xv.y + cv.y + bv.y;
        r[c][2] = xv.z + cv.z + bv.z; r[c][3] = xv.w + cv.w + bv.w;
        #pragma unroll
        for (int i = 0; i < 4; ++i) { s += r[c][i]; ss += r[c][i]*r[c][i]; }
    }
    #pragma unroll
    for (int m = 1; m < 64; m <<= 1) { s += __shfl_xor(s, m, 64); ss += __shfl_xor(ss, m, 64); }
    float mean = s * (1.f/1024.f);
    float var  = ss * (1.f/1024.f) - mean*mean;
    float inv  = rsqrtf(var + 1e-5f);

    float x1[4][4];
    #pragma unroll
    for (int c = 0; c < 4; ++c) {
        int e = c*256 + lane*4;
        #pragma unroll
        for (int i = 0; i < 4; ++i)
            x1[c][i] = (r[c][i] - mean)*inv*g1[e+i] + be1[e+i];
    }

    // quantum FFN: elems 0..7 live in lanes 0 (e=0..3) and 1 (e=4..7), chunk 0
    float pf = 0.f;
    if (lane < 2) {
        #pragma unroll
        for (int i = 0; i < 4; ++i) {
            int e = lane*4 + i;
            pf += cosf(x1[0][i]) * cosf(theta[e]) * w1v[e];
        }
    }
    pf += __shfl_xor(pf, 1, 64);
    float f = __shfl(pf, 0, 64) + b1v[0];

    float s2 = 0.f, ss2 = 0.f;
    #pragma unroll
    for (int c = 0; c < 4; ++c)
        #pragma unroll
        for (int i = 0; i < 4; ++i) {
            float v2 = x1[c][i] + f; s2 += v2; ss2 += v2*v2;
        }
    #pragma unroll
    for (int m = 1; m < 64; m <<= 1) { s2 += __shfl_xor(s2, m, 64); ss2 += __shfl_xor(ss2, m, 64); }
    float mean2 = s2 * (1.f/1024.f);
    float var2  = ss2 * (1.f/1024.f) - mean2*mean2;
    float inv2  = rsqrtf(var2 + 1e-5f);

    #pragma unroll
    for (int c = 0; c < 4; ++c) {
        int e = c*256 + lane*4;
        float4 ov;
        ov.x = ((x1[c][0] + f) - mean2)*inv2*g2[e+0] + be2[e+0];
        ov.y = ((x1[c][1] + f) - mean2)*inv2*g2[e+1] + be2[e+1];
        ov.z = ((x1[c][2] + f) - mean2)*inv2*g2[e+2] + be2[e+2];
        ov.w = ((x1[c][3] + f) - mean2)*inv2*g2[e+3] + be2[e+3];
        *(float4*)(out + (size_t)t*EMB + e) = ov;
    }
}

extern "C" void kernel_launch(void* const* d_in, const int* in_sizes, int n_in,
                              void* d_out, int out_size, void* d_ws, size_t ws_size,
                              hipStream_t stream)
{
    const float* x      = (const float*)d_in[0];
    const float* w_qkv  = (const float*)d_in[1];
    const float* w_comb = (const float*)d_in[2];
    const float* b_comb = (const float*)d_in[3];
    const float* g1     = (const float*)d_in[4];
    const float* be1    = (const float*)d_in[5];
    const float* g2     = (const float*)d_in[6];
    const float* be2    = (const float*)d_in[7];
    const float* theta  = (const float*)d_in[8];
    const float* w1v    = (const float*)d_in[9];
    const float* b1v    = (const float*)d_in[10];
    float* out = (float*)d_out;

    char* ws = (char*)d_ws;
    bf16*  xb     = (bf16*)(ws);                    // [ 0,  8) MB
    bf16*  wqkvb  = (bf16*)(ws + ( 8u<<20));        // [ 8, 14) MB
    bf16*  wcombb = (bf16*)(ws + (14u<<20));        // [14, 16) MB
    bf16*  qb     = (bf16*)(ws + (16u<<20));        // [16, 24) MB
    bf16*  kb     = (bf16*)(ws + (24u<<20));        // [24, 32) MB
    bf16*  vtb    = (bf16*)(ws + (32u<<20));        // [32, 40) MB
    bf16*  attn   = (bf16*)(ws + (40u<<20));        // [40, 48) MB
    float* comb   = (float*)(ws + (16u<<20));       // [16, 32) MB (aliases dead q,k)

    convert3<<<dim3(2048, 3), 256, 0, stream>>>(x, w_qkv, w_comb, xb, wqkvb, wcombb);

    gemm_bt<0,128><<<dim3(3*EMB/128, NTOK/128), 256, 0, stream>>>(
        xb, wqkvb, qb, kb, vtb, nullptr, EMB);
    attn_kernel<<<dim3(SEQ/128, NB*NH), 512, 0, stream>>>(qb, kb, vtb, attn);
    gemm_bt<1,64><<<dim3(EMB/128, NTOK/64), 256, 0, stream>>>(
        attn, wcombb, nullptr, nullptr, nullptr, comb, EMB);
    ln_kernel<<<NTOK/4, 256, 0, stream>>>(x, comb, b_comb, g1, be1, g2, be2,
                                          theta, w1v, b1v, out);
}